// Round 1
// baseline (1092.117 us; speedup 1.0000x reference)
//
#include <hip/hip_runtime.h>

#define NN      25000
#define TWO_N   50000
#define TT      8
#define CIN     32
#define ROWF    256      // TT*CIN floats per node row
#define COUT    64
#define FTOT    224
#define NEDGE   800000

// ---- CSR build ----
__global__ void hist_kernel(const int* __restrict__ dst, int* __restrict__ counts) {
    int i = blockIdx.x * blockDim.x + threadIdx.x;
    if (i < NEDGE) atomicAdd(&counts[dst[i]], 1);
}

__global__ void scan_kernel(const int* __restrict__ counts, int* __restrict__ row_ptr) {
    __shared__ int lds[1024];
    __shared__ int s_carry;
    if (threadIdx.x == 0) s_carry = 0;
    __syncthreads();
    for (int base = 0; base < TWO_N; base += 1024) {
        int i = base + (int)threadIdx.x;
        int v = (i < TWO_N) ? counts[i] : 0;
        lds[threadIdx.x] = v;
        __syncthreads();
        for (int off = 1; off < 1024; off <<= 1) {
            int t = ((int)threadIdx.x >= off) ? lds[threadIdx.x - off] : 0;
            __syncthreads();
            lds[threadIdx.x] += t;
            __syncthreads();
        }
        int incl = lds[threadIdx.x];
        int carry = s_carry;
        if (i < TWO_N) row_ptr[i] = carry + incl - v;   // exclusive scan
        __syncthreads();
        if (threadIdx.x == 1023) s_carry = carry + lds[1023];
        __syncthreads();
    }
    if (threadIdx.x == 0) row_ptr[TWO_N] = s_carry;
}

__global__ void scatter_kernel(const int* __restrict__ src, const int* __restrict__ dst,
                               const float* __restrict__ ef, const int* __restrict__ row_ptr,
                               int* __restrict__ fill, int* __restrict__ ssrc,
                               float* __restrict__ sef) {
    int i = blockIdx.x * blockDim.x + threadIdx.x;
    if (i < NEDGE) {
        int d = dst[i];
        int p = row_ptr[d] + atomicAdd(&fill[d], 1);
        ssrc[p] = src[i];
        sef[p]  = ef[i];
    }
}

// ---- SpMM: one wave per dst node; out[node] = scale*sum(ef*hin[src]) - sub[node'] ----
__global__ __launch_bounds__(256) void spmm_kernel(
        const int* __restrict__ row_ptr, const int* __restrict__ ssrc,
        const float* __restrict__ sef,
        const float* __restrict__ hin, int wrap_in,
        const float* __restrict__ sub, int wrap_sub,
        float scale, float* __restrict__ out) {
    int wid  = (int)((blockIdx.x * blockDim.x + threadIdx.x) >> 6);
    int lane = threadIdx.x & 63;
    if (wid >= TWO_N) return;
    int beg = row_ptr[wid], end = row_ptr[wid + 1];
    float4 acc = make_float4(0.f, 0.f, 0.f, 0.f);
    for (int e = beg; e < end; ++e) {
        int s   = ssrc[e];
        float w = sef[e];
        if (wrap_in && s >= NN) s -= NN;
        float4 v = ((const float4*)(hin + (size_t)s * ROWF))[lane];
        acc.x = fmaf(w, v.x, acc.x);
        acc.y = fmaf(w, v.y, acc.y);
        acc.z = fmaf(w, v.z, acc.z);
        acc.w = fmaf(w, v.w, acc.w);
    }
    float4 r;
    if (sub != nullptr) {
        int sn = wid;
        if (wrap_sub && sn >= NN) sn -= NN;
        float4 sv = ((const float4*)(sub + (size_t)sn * ROWF))[lane];
        r.x = scale * acc.x - sv.x;
        r.y = scale * acc.y - sv.y;
        r.z = scale * acc.z - sv.z;
        r.w = scale * acc.w - sv.w;
    } else {
        r = acc;
    }
    ((float4*)(out + (size_t)wid * ROWF))[lane] = r;
}

// ---- Output matmul: h(N*T, 224) @ W(224,64) + b; one wave per row, grid-stride ----
__global__ __launch_bounds__(256) void out_kernel(
        const float* __restrict__ feat, const float* __restrict__ X1,
        const float* __restrict__ X2, const float* __restrict__ X3,
        const float* __restrict__ W, const float* __restrict__ b,
        float* __restrict__ out) {
    __shared__ float Wl[FTOT * COUT];
    for (int i = threadIdx.x; i < FTOT * COUT; i += blockDim.x) Wl[i] = W[i];
    __syncthreads();
    int lane = threadIdx.x & 63;
    int waves_total = gridDim.x * (blockDim.x >> 6);
    int wid0 = blockIdx.x * (blockDim.x >> 6) + (threadIdx.x >> 6);
    float bias = b[lane];
    for (int row = wid0; row < NN * TT; row += waves_total) {
        int i = row >> 3;   // node
        int t = row & 7;    // time
        size_t o_lo = ((size_t)i * TT + t) * CIN;
        size_t o_hi = ((size_t)(i + NN) * TT + t) * CIN;
        const float* ps[7] = { feat + o_lo, X1 + o_lo, X1 + o_hi,
                               X2 + o_lo, X2 + o_hi, X3 + o_lo, X3 + o_hi };
        float acc = bias;
        #pragma unroll
        for (int a = 0; a < 7; ++a) {
            const float4* p = (const float4*)ps[a];
            #pragma unroll
            for (int c4 = 0; c4 < 8; ++c4) {
                float4 v = p[c4];
                int f = a * CIN + c4 * 4;
                acc = fmaf(v.x, Wl[(f + 0) * COUT + lane], acc);
                acc = fmaf(v.y, Wl[(f + 1) * COUT + lane], acc);
                acc = fmaf(v.z, Wl[(f + 2) * COUT + lane], acc);
                acc = fmaf(v.w, Wl[(f + 3) * COUT + lane], acc);
            }
        }
        out[(size_t)row * COUT + lane] = acc;
    }
}

extern "C" void kernel_launch(void* const* d_in, const int* in_sizes, int n_in,
                              void* d_out, int out_size, void* d_ws, size_t ws_size,
                              hipStream_t stream) {
    const float* feat = (const float*)d_in[0];
    const float* ef   = (const float*)d_in[1];
    const float* W    = (const float*)d_in[2];
    const float* b    = (const float*)d_in[3];
    const int*   src  = (const int*)d_in[4];
    const int*   dst  = (const int*)d_in[5];
    float* out = (float*)d_out;

    // Workspace layout (≈160.4 MB total)
    float* X1 = (float*)d_ws;
    float* X2 = X1 + (size_t)TWO_N * ROWF;
    float* X3 = X2 + (size_t)TWO_N * ROWF;
    int* row_ptr = (int*)(X3 + (size_t)TWO_N * ROWF);
    int* counts  = row_ptr + TWO_N + 64;
    int* ssrc    = counts  + TWO_N + 64;
    float* sef   = (float*)(ssrc + NEDGE);

    // CSR build (by dst)
    hipMemsetAsync(counts, 0, TWO_N * sizeof(int), stream);
    hist_kernel<<<(NEDGE + 255) / 256, 256, 0, stream>>>(dst, counts);
    scan_kernel<<<1, 1024, 0, stream>>>(counts, row_ptr);
    hipMemsetAsync(counts, 0, TWO_N * sizeof(int), stream);
    scatter_kernel<<<(NEDGE + 255) / 256, 256, 0, stream>>>(src, dst, ef, row_ptr,
                                                            counts, ssrc, sef);

    // Chebyshev diffusion steps
    int spmm_grid = (TWO_N + 3) / 4;   // 4 waves per 256-thread block
    spmm_kernel<<<spmm_grid, 256, 0, stream>>>(row_ptr, ssrc, sef,
                                               feat, 1, nullptr, 0, 1.0f, X1);
    spmm_kernel<<<spmm_grid, 256, 0, stream>>>(row_ptr, ssrc, sef,
                                               X1, 0, feat, 1, 2.0f, X2);
    spmm_kernel<<<spmm_grid, 256, 0, stream>>>(row_ptr, ssrc, sef,
                                               X2, 0, X1, 0, 2.0f, X3);

    // Output projection
    out_kernel<<<1024, 256, 0, stream>>>(feat, X1, X2, X3, W, b, out);
}